// Round 5
// baseline (2498.697 us; speedup 1.0000x reference)
//
#include <hip/hip_runtime.h>

// LSTM (B=512, T=1024, I=64, H=128) + FC(128->256->1), fp32 in/out.
// 32 blocks x 1024 threads (1 block/CU, 4 waves/SIMD). Block owns 16 batch
// rows (full N=16 MFMA cols) and all 512 gate rows. Wave w owns M-tiles
// {16w, 256+16w}. Stationary weights: Whi (f16) ONLY = 12 frags = 48 VGPRs
// (round-4 postmortem: 80-VGPR stationary set spilled to scratch and the
// per-step scratch reloads at ~200cyc L2 latency were ~4000 of 5520 cyc/step).
// Precision: W quantized to f16 (2^-12 rel), v = [x|h] carried EXACTLY as
// hi+lo f16 pair; both lo-terms multiply the SAME Whi registers. Mirror of
// round-4's measured 4.88e-4 error structure -> predicted absmax ~5e-4.

#define T_STEPS 1024
#define ISZ 64
#define HSZ 128
#define NB 16          // batch rows per block
#define NTH 1024
#define VSTR 200       // f16 row stride (192 + 8 pad)
#define GSTR 516       // f32 gbuf row stride (512 + 4 pad)

typedef _Float16 f16x8 __attribute__((ext_vector_type(8)));
typedef _Float16 f16x2 __attribute__((ext_vector_type(2)));
typedef float    f32x4 __attribute__((ext_vector_type(4)));

__device__ __forceinline__ float fast_sigmoid(float x) {
    return 1.0f / (1.0f + __expf(-x));
}
__device__ __forceinline__ float fast_tanh(float x) {
    float xc = fminf(fmaxf(x, -15.0f), 15.0f);
    float u = __expf(2.0f * xc);
    return (u - 1.0f) / (u + 1.0f);
}

__global__ __launch_bounds__(NTH, 4)   // 4 waves/EU -> 128-VGPR cap
void lstm_f16_kernel(const float* __restrict__ x,
                     const float* __restrict__ W_ih,
                     const float* __restrict__ W_hh,
                     const float* __restrict__ b_ih,
                     const float* __restrict__ b_hh,
                     const float* __restrict__ W1,
                     const float* __restrict__ b1,
                     const float* __restrict__ W2,
                     const float* __restrict__ b2,
                     float* __restrict__ out)
{
    __shared__ __align__(16) _Float16 vhi[NB][VSTR];   // k 0..63: x hi, 64..191: h hi
    __shared__ __align__(16) _Float16 vlo[NB][VSTR];   // k 0..63: x lo, 64..191: h lo
    __shared__ __align__(16) float    gbuf[NB][GSTR];  // activated gates, batch-major
    __shared__ __align__(16) float    hbuf[NB][HSZ];   // fp32 h at final step

    const int tid  = threadIdx.x;
    const int lane = tid & 63;
    const int w    = tid >> 6;       // wave 0..15
    const int n    = lane & 15;      // batch col (B/D) == A row-within-tile
    const int quad = lane >> 4;      // 0..3
    const int b0   = blockIdx.x * NB;

    const int m1 = 16 * w;           // tile1 rows [m1,m1+16): i (w<8) / f (w>=8)
    const int m2 = 256 + 16 * w;     // tile2: g (w<8, tanh) / o (w>=8, sigmoid)

    // ---- one-time: stationary Whi f16 A-frags (48 VGPRs) ----
    f16x8 wa[6], wb[6];
    {
        const int g1 = m1 + n;
        const int g2 = m2 + n;
        #pragma unroll
        for (int ks = 0; ks < 6; ++ks) {
            #pragma unroll
            for (int j = 0; j < 8; ++j) {
                const int k = ks * 32 + quad * 8 + j;
                float v1 = (k < ISZ) ? W_ih[(size_t)g1 * ISZ + k]
                                     : W_hh[(size_t)g1 * HSZ + (k - ISZ)];
                float v2 = (k < ISZ) ? W_ih[(size_t)g2 * ISZ + k]
                                     : W_hh[(size_t)g2 * HSZ + (k - ISZ)];
                wa[ks][j] = (_Float16)v1;
                wb[ks][j] = (_Float16)v2;
            }
        }
    }
    // ---- bias in registers (8 VGPRs) ----
    f32x4 bias_a, bias_b;
    #pragma unroll
    for (int r = 0; r < 4; ++r) {
        bias_a[r] = b_ih[m1 + quad * 4 + r] + b_hh[m1 + quad * 4 + r];
        bias_b[r] = b_ih[m2 + quad * 4 + r] + b_hh[m2 + quad * 4 + r];
    }

    // ---- init LDS: zero h region (hi+lo), stage x(0), prefetch x(1) ----
    {
        const int rb = tid >> 6, jj = (tid & 63) * 2;
        *(f16x2*)&vhi[rb][ISZ + jj] = (f16x2){(_Float16)0.0f, (_Float16)0.0f};
        *(f16x2*)&vlo[rb][ISZ + jj] = (f16x2){(_Float16)0.0f, (_Float16)0.0f};
    }
    {
        float xv = x[((size_t)(b0 + w) * T_STEPS + 0) * ISZ + lane];
        _Float16 hi = (_Float16)xv;
        vhi[w][lane] = hi;
        vlo[w][lane] = (_Float16)(xv - (float)hi);
    }
    float xa = x[((size_t)(b0 + w) * T_STEPS + 1) * ISZ + lane];  // for t=1
    float c0 = 0.0f, c1 = 0.0f;      // cell state: thread owns (b=w, j=2*lane, 2*lane+1)
    const int tanh_sel = (w < 8);
    __syncthreads();

    const _Float16* vh = &vhi[n][quad * 8];
    const _Float16* vl = &vlo[n][quad * 8];

    #pragma unroll 1
    for (int t = 0; t < T_STEPS; ++t) {
        // distance-2 x prefetch (issue now, store at step t+1's phase C)
        float xb = 0.0f;
        if (t + 2 < T_STEPS)
            xb = x[((size_t)(b0 + w) * T_STEPS + (t + 2)) * ISZ + lane];

        // ---- MFMA phase: 24 MFMAs, Whi x (v_hi + v_lo), K=192 ----
        f32x4 acc1 = bias_a, acc2 = bias_b;
        #pragma unroll
        for (int ks = 0; ks < 6; ++ks) {
            f16x8 bh = *(const f16x8*)(vh + ks * 32);
            f16x8 bl = *(const f16x8*)(vl + ks * 32);
            acc1 = __builtin_amdgcn_mfma_f32_16x16x32_f16(wa[ks], bh, acc1, 0, 0, 0);
            acc2 = __builtin_amdgcn_mfma_f32_16x16x32_f16(wb[ks], bh, acc2, 0, 0, 0);
            acc1 = __builtin_amdgcn_mfma_f32_16x16x32_f16(wa[ks], bl, acc1, 0, 0, 0);
            acc2 = __builtin_amdgcn_mfma_f32_16x16x32_f16(wb[ks], bl, acc2, 0, 0, 0);
        }

        // ---- epilogue: activate + write gates (D: col=lane&15, row=quad*4+r) ----
        {
            f32x4 g1, g2;
            #pragma unroll
            for (int r = 0; r < 4; ++r) g1[r] = fast_sigmoid(acc1[r]);          // i / f
            #pragma unroll
            for (int r = 0; r < 4; ++r)
                g2[r] = tanh_sel ? fast_tanh(acc2[r]) : fast_sigmoid(acc2[r]);  // g / o
            *(f32x4*)&gbuf[n][m1 + quad * 4] = g1;
            *(f32x4*)&gbuf[n][m2 + quad * 4] = g2;
        }
        __syncthreads();   // A: gates visible; all v reads of step t complete

        // ---- phase C: wave w updates batch row w, thread owns j = 2*lane, 2*lane+1 ----
        {
            const int j0 = 2 * lane;
            float2 ig = *(const float2*)&gbuf[w][j0];
            float2 fg = *(const float2*)&gbuf[w][HSZ + j0];
            float2 gg = *(const float2*)&gbuf[w][2 * HSZ + j0];
            float2 og = *(const float2*)&gbuf[w][3 * HSZ + j0];
            c0 = fmaf(fg.x, c0, ig.x * gg.x);
            c1 = fmaf(fg.y, c1, ig.y * gg.y);
            float h0 = og.x * fast_tanh(c0);
            float h1 = og.y * fast_tanh(c1);
            _Float16 h0h = (_Float16)h0, h1h = (_Float16)h1;
            *(f16x2*)&vhi[w][ISZ + j0] = (f16x2){h0h, h1h};
            *(f16x2*)&vlo[w][ISZ + j0] =
                (f16x2){(_Float16)(h0 - (float)h0h), (_Float16)(h1 - (float)h1h)};
            if (t == T_STEPS - 1) {
                float2 hv; hv.x = h0; hv.y = h1;
                *(float2*)&hbuf[w][j0] = hv;
            }
        }
        if (t + 1 < T_STEPS) {       // store x(t+1) staged last step
            _Float16 xh = (_Float16)xa;
            vhi[w][lane] = xh;
            vlo[w][lane] = (_Float16)(xa - (float)xh);
        }
        xa = xb;
        __syncthreads();   // B: v ready for step t+1
    }

    // ---- FC head: wave w computes out[b0+w] ----
    {
        float z = 0.0f;
        #pragma unroll
        for (int s = 0; s < 4; ++s) {
            const int m = lane + 64 * s;
            const float4* w1r = reinterpret_cast<const float4*>(W1 + (size_t)m * HSZ);
            const float4* hr  = reinterpret_cast<const float4*>(hbuf[w]);
            float dot = 0.0f;
            #pragma unroll
            for (int k = 0; k < HSZ / 4; ++k) {
                float4 wv = w1r[k];
                float4 hv = hr[k];
                dot = fmaf(wv.x, hv.x, dot);
                dot = fmaf(wv.y, hv.y, dot);
                dot = fmaf(wv.z, hv.z, dot);
                dot = fmaf(wv.w, hv.w, dot);
            }
            z = fmaf(W2[m], dot + b1[m], z);
        }
        #pragma unroll
        for (int off = 32; off >= 1; off >>= 1)
            z += __shfl_down(z, off, 64);
        if (lane == 0) out[b0 + w] = z + b2[0];
    }
}

extern "C" void kernel_launch(void* const* d_in, const int* in_sizes, int n_in,
                              void* d_out, int out_size, void* d_ws, size_t ws_size,
                              hipStream_t stream) {
    const float* x    = (const float*)d_in[0];
    const float* W_ih = (const float*)d_in[1];
    const float* W_hh = (const float*)d_in[2];
    const float* b_ih = (const float*)d_in[3];
    const float* b_hh = (const float*)d_in[4];
    const float* W1   = (const float*)d_in[5];
    const float* b1   = (const float*)d_in[6];
    const float* W2   = (const float*)d_in[7];
    const float* b2   = (const float*)d_in[8];
    float* out = (float*)d_out;

    lstm_f16_kernel<<<dim3(512 / NB), dim3(NTH), 0, stream>>>(
        x, W_ih, W_hh, b_ih, b_hh, W1, b1, W2, b2, out);
}

// Round 6
// 2494.132 us; speedup vs baseline: 1.0018x; 1.0018x over previous
//
#include <hip/hip_runtime.h>

// LSTM (B=512, T=1024, I=64, H=128) + FC(128->256->1), fp32 in/out.
// 32 blocks x 1024 threads (1 block/CU, 4 waves/SIMD). Block owns 16 batch
// rows (full N=16 MFMA cols) and all 512 gate rows. Wave w owns M-tiles
// {16w, 256+16w}. Stationary weights: Whi (f16) = 12 frags = 48 VGPRs.
// ROUND 6 CHANGE (only): amdgpu_waves_per_eu(4,4). Rounds 4/5 showed
// VGPR_Count=64 — the allocator targeted 8 waves/EU (2 blocks/CU fit by
// LDS+waves) and evicted the stationary weights, reloading them every step.
// Pinning waves/EU to exactly 4 raises the budget to 128 VGPRs so the
// 48-reg weight set (+8 bias +8 acc) stays resident.
// Precision: W quantized to f16, v = [x|h] carried exactly as hi+lo f16
// pair; both lo-terms multiply the same Whi registers. Measured 4.88e-4.

#define T_STEPS 1024
#define ISZ 64
#define HSZ 128
#define NB 16          // batch rows per block
#define NTH 1024
#define VSTR 200       // f16 row stride (192 + 8 pad)
#define GSTR 516       // f32 gbuf row stride (512 + 4 pad)

typedef _Float16 f16x8 __attribute__((ext_vector_type(8)));
typedef _Float16 f16x2 __attribute__((ext_vector_type(2)));
typedef float    f32x4 __attribute__((ext_vector_type(4)));

__device__ __forceinline__ float fast_sigmoid(float x) {
    return 1.0f / (1.0f + __expf(-x));
}
__device__ __forceinline__ float fast_tanh(float x) {
    float xc = fminf(fmaxf(x, -15.0f), 15.0f);
    float u = __expf(2.0f * xc);
    return (u - 1.0f) / (u + 1.0f);
}

__global__ __launch_bounds__(NTH)
__attribute__((amdgpu_waves_per_eu(4, 4)))   // exactly 4 waves/EU -> 128-VGPR budget
void lstm_f16_kernel(const float* __restrict__ x,
                     const float* __restrict__ W_ih,
                     const float* __restrict__ W_hh,
                     const float* __restrict__ b_ih,
                     const float* __restrict__ b_hh,
                     const float* __restrict__ W1,
                     const float* __restrict__ b1,
                     const float* __restrict__ W2,
                     const float* __restrict__ b2,
                     float* __restrict__ out)
{
    __shared__ __align__(16) _Float16 vhi[NB][VSTR];   // k 0..63: x hi, 64..191: h hi
    __shared__ __align__(16) _Float16 vlo[NB][VSTR];   // k 0..63: x lo, 64..191: h lo
    __shared__ __align__(16) float    gbuf[NB][GSTR];  // activated gates, batch-major
    __shared__ __align__(16) float    hbuf[NB][HSZ];   // fp32 h at final step

    const int tid  = threadIdx.x;
    const int lane = tid & 63;
    const int w    = tid >> 6;       // wave 0..15
    const int n    = lane & 15;      // batch col (B/D) == A row-within-tile
    const int quad = lane >> 4;      // 0..3
    const int b0   = blockIdx.x * NB;

    const int m1 = 16 * w;           // tile1 rows [m1,m1+16): i (w<8) / f (w>=8)
    const int m2 = 256 + 16 * w;     // tile2: g (w<8, tanh) / o (w>=8, sigmoid)

    // ---- one-time: stationary Whi f16 A-frags (48 VGPRs) ----
    f16x8 wa[6], wb[6];
    {
        const int g1 = m1 + n;
        const int g2 = m2 + n;
        #pragma unroll
        for (int ks = 0; ks < 6; ++ks) {
            #pragma unroll
            for (int j = 0; j < 8; ++j) {
                const int k = ks * 32 + quad * 8 + j;
                float v1 = (k < ISZ) ? W_ih[(size_t)g1 * ISZ + k]
                                     : W_hh[(size_t)g1 * HSZ + (k - ISZ)];
                float v2 = (k < ISZ) ? W_ih[(size_t)g2 * ISZ + k]
                                     : W_hh[(size_t)g2 * HSZ + (k - ISZ)];
                wa[ks][j] = (_Float16)v1;
                wb[ks][j] = (_Float16)v2;
            }
        }
    }
    // ---- bias in registers (8 VGPRs) ----
    f32x4 bias_a, bias_b;
    #pragma unroll
    for (int r = 0; r < 4; ++r) {
        bias_a[r] = b_ih[m1 + quad * 4 + r] + b_hh[m1 + quad * 4 + r];
        bias_b[r] = b_ih[m2 + quad * 4 + r] + b_hh[m2 + quad * 4 + r];
    }

    // ---- init LDS: zero h region (hi+lo), stage x(0), prefetch x(1) ----
    {
        const int rb = tid >> 6, jj = (tid & 63) * 2;
        *(f16x2*)&vhi[rb][ISZ + jj] = (f16x2){(_Float16)0.0f, (_Float16)0.0f};
        *(f16x2*)&vlo[rb][ISZ + jj] = (f16x2){(_Float16)0.0f, (_Float16)0.0f};
    }
    {
        float xv = x[((size_t)(b0 + w) * T_STEPS + 0) * ISZ + lane];
        _Float16 hi = (_Float16)xv;
        vhi[w][lane] = hi;
        vlo[w][lane] = (_Float16)(xv - (float)hi);
    }
    float xa = x[((size_t)(b0 + w) * T_STEPS + 1) * ISZ + lane];  // for t=1
    float c0 = 0.0f, c1 = 0.0f;      // cell state: thread owns (b=w, j=2*lane, 2*lane+1)
    const int tanh_sel = (w < 8);
    __syncthreads();

    const _Float16* vh = &vhi[n][quad * 8];
    const _Float16* vl = &vlo[n][quad * 8];

    #pragma unroll 1
    for (int t = 0; t < T_STEPS; ++t) {
        // distance-2 x prefetch (issue now, store at step t+1's phase C)
        float xb = 0.0f;
        if (t + 2 < T_STEPS)
            xb = x[((size_t)(b0 + w) * T_STEPS + (t + 2)) * ISZ + lane];

        // ---- MFMA phase: 24 MFMAs, Whi x (v_hi + v_lo), K=192 ----
        f32x4 acc1 = bias_a, acc2 = bias_b;
        #pragma unroll
        for (int ks = 0; ks < 6; ++ks) {
            f16x8 bh = *(const f16x8*)(vh + ks * 32);
            f16x8 bl = *(const f16x8*)(vl + ks * 32);
            acc1 = __builtin_amdgcn_mfma_f32_16x16x32_f16(wa[ks], bh, acc1, 0, 0, 0);
            acc2 = __builtin_amdgcn_mfma_f32_16x16x32_f16(wb[ks], bh, acc2, 0, 0, 0);
            acc1 = __builtin_amdgcn_mfma_f32_16x16x32_f16(wa[ks], bl, acc1, 0, 0, 0);
            acc2 = __builtin_amdgcn_mfma_f32_16x16x32_f16(wb[ks], bl, acc2, 0, 0, 0);
        }

        // ---- epilogue: activate + write gates (D: col=lane&15, row=quad*4+r) ----
        {
            f32x4 g1, g2;
            #pragma unroll
            for (int r = 0; r < 4; ++r) g1[r] = fast_sigmoid(acc1[r]);          // i / f
            #pragma unroll
            for (int r = 0; r < 4; ++r)
                g2[r] = tanh_sel ? fast_tanh(acc2[r]) : fast_sigmoid(acc2[r]);  // g / o
            *(f32x4*)&gbuf[n][m1 + quad * 4] = g1;
            *(f32x4*)&gbuf[n][m2 + quad * 4] = g2;
        }
        __syncthreads();   // A: gates visible; all v reads of step t complete

        // ---- phase C: wave w updates batch row w, thread owns j = 2*lane, 2*lane+1 ----
        {
            const int j0 = 2 * lane;
            float2 ig = *(const float2*)&gbuf[w][j0];
            float2 fg = *(const float2*)&gbuf[w][HSZ + j0];
            float2 gg = *(const float2*)&gbuf[w][2 * HSZ + j0];
            float2 og = *(const float2*)&gbuf[w][3 * HSZ + j0];
            c0 = fmaf(fg.x, c0, ig.x * gg.x);
            c1 = fmaf(fg.y, c1, ig.y * gg.y);
            float h0 = og.x * fast_tanh(c0);
            float h1 = og.y * fast_tanh(c1);
            _Float16 h0h = (_Float16)h0, h1h = (_Float16)h1;
            *(f16x2*)&vhi[w][ISZ + j0] = (f16x2){h0h, h1h};
            *(f16x2*)&vlo[w][ISZ + j0] =
                (f16x2){(_Float16)(h0 - (float)h0h), (_Float16)(h1 - (float)h1h)};
            if (t == T_STEPS - 1) {
                float2 hv; hv.x = h0; hv.y = h1;
                *(float2*)&hbuf[w][j0] = hv;
            }
        }
        if (t + 1 < T_STEPS) {       // store x(t+1) staged last step
            _Float16 xh = (_Float16)xa;
            vhi[w][lane] = xh;
            vlo[w][lane] = (_Float16)(xa - (float)xh);
        }
        xa = xb;
        __syncthreads();   // B: v ready for step t+1
    }

    // ---- FC head: wave w computes out[b0+w] ----
    {
        float z = 0.0f;
        #pragma unroll
        for (int s = 0; s < 4; ++s) {
            const int m = lane + 64 * s;
            const float4* w1r = reinterpret_cast<const float4*>(W1 + (size_t)m * HSZ);
            const float4* hr  = reinterpret_cast<const float4*>(hbuf[w]);
            float dot = 0.0f;
            #pragma unroll
            for (int k = 0; k < HSZ / 4; ++k) {
                float4 wv = w1r[k];
                float4 hv = hr[k];
                dot = fmaf(wv.x, hv.x, dot);
                dot = fmaf(wv.y, hv.y, dot);
                dot = fmaf(wv.z, hv.z, dot);
                dot = fmaf(wv.w, hv.w, dot);
            }
            z = fmaf(W2[m], dot + b1[m], z);
        }
        #pragma unroll
        for (int off = 32; off >= 1; off >>= 1)
            z += __shfl_down(z, off, 64);
        if (lane == 0) out[b0 + w] = z + b2[0];
    }
}

extern "C" void kernel_launch(void* const* d_in, const int* in_sizes, int n_in,
                              void* d_out, int out_size, void* d_ws, size_t ws_size,
                              hipStream_t stream) {
    const float* x    = (const float*)d_in[0];
    const float* W_ih = (const float*)d_in[1];
    const float* W_hh = (const float*)d_in[2];
    const float* b_ih = (const float*)d_in[3];
    const float* b_hh = (const float*)d_in[4];
    const float* W1   = (const float*)d_in[5];
    const float* b1   = (const float*)d_in[6];
    const float* W2   = (const float*)d_in[7];
    const float* b2   = (const float*)d_in[8];
    float* out = (float*)d_out;

    lstm_f16_kernel<<<dim3(512 / NB), dim3(NTH), 0, stream>>>(
        x, W_ih, W_hh, b_ih, b_hh, W1, b1, W2, b2, out);
}